// Round 19
// baseline (178.919 us; speedup 1.0000x reference)
//
#include <hip/hip_runtime.h>

#define D 128
#define BM 64
#define SLOT 2048

typedef short short8 __attribute__((ext_vector_type(8)));
typedef unsigned short ushort8_t __attribute__((ext_vector_type(8)));
typedef float f32x4 __attribute__((ext_vector_type(4)));

__device__ __forceinline__ unsigned short f2bf(float x) {
    unsigned u = __float_as_uint(x);
    unsigned r = (u + 0x7fffu + ((u >> 16) & 1u)) >> 16;   // RNE
    return (unsigned short)r;
}
__device__ __forceinline__ float bf2f(unsigned short u) {
    return __uint_as_float(((unsigned)u) << 16);
}

// ===========================================================================
// PREP: features fp32->bf16 + WT build. Grid-stride; launch wide (1024 blk).
// ===========================================================================
__global__ __launch_bounds__(256) void prep_kernel(
    const float4* __restrict__ feat4, ushort4* __restrict__ fbf4, int nf4,
    const float* __restrict__ W1, const float* __restrict__ W2,
    unsigned short* __restrict__ WT)
{
    const int t = threadIdx.x;
    const int b = blockIdx.x;
    const int stride = gridDim.x * 256;

    for (int i = b * 256 + t; i < nf4; i += stride) {
        float4 v = feat4[i];
        fbf4[i] = make_ushort4(f2bf(v.x), f2bf(v.y), f2bf(v.z), f2bf(v.w));
    }

    if (b < 128) {
        int idx = b * 256 + t;
        int c = idx & 127;
        int k = idx >> 7;
        float w = (k < 128) ? W1[k * 128 + c] : W2[(k - 128) * 128 + c];
        WT[c * 256 + k] = f2bf(w);
    }
}

// ===========================================================================
// Standalone fconv/wconv (fallback tiers)
// ===========================================================================
__global__ __launch_bounds__(256) void fconv_kernel(
    const float4* __restrict__ feat4, ushort4* __restrict__ fbf4, int total)
{
    int i = blockIdx.x * 256 + threadIdx.x;
    if (i < total) {
        float4 v = feat4[i];
        fbf4[i] = make_ushort4(f2bf(v.x), f2bf(v.y), f2bf(v.z), f2bf(v.w));
    }
}

__global__ __launch_bounds__(256) void wconv_kernel(
    const float* __restrict__ W1, const float* __restrict__ W2,
    unsigned short* __restrict__ WT)
{
    int idx = blockIdx.x * 256 + threadIdx.x;
    int c = idx & 127;
    int k = idx >> 7;
    float w = (k < 128) ? W1[k * 128 + c] : W2[(k - 128) * 128 + c];
    WT[c * 256 + k] = f2bf(w);
}

// ===========================================================================
// Bucket scatter into PADDED slots: bucket b owns bsedge[b*SLOT .. +SLOT).
// gcur[b] (zeroed) is cursor and, afterwards, the bucket count.
// EPB=2048 (grid 2x round-17 for latency hiding). Key=(r&63)<<17|col.
// ===========================================================================
__global__ __launch_bounds__(256) void bucket_scatter_kernel(
    const int* __restrict__ rows, const int* __restrict__ cols,
    const float* __restrict__ vals, int* __restrict__ gcur,
    uint2* __restrict__ bsedge, int E, int nb)
{
    __shared__ int cnt[2048];
    __shared__ int base[2048];
    int t = threadIdx.x;
    int e0 = blockIdx.x * 2048;
    for (int i = t; i < nb; i += 256) cnt[i] = 0;
    __syncthreads();
    #pragma unroll
    for (int q = 0; q < 8; ++q) {
        int e = e0 + t + q * 256;
        if (e < E) atomicAdd(&cnt[rows[e] >> 6], 1);
    }
    __syncthreads();
    for (int i = t; i < nb; i += 256) {
        int c = cnt[i];
        if (c) { base[i] = atomicAdd(&gcur[i], c); cnt[i] = 0; }
    }
    __syncthreads();
    #pragma unroll
    for (int q = 0; q < 8; ++q) {
        int e = e0 + t + q * 256;
        if (e < E) {
            int r = rows[e];
            int b = r >> 6;
            int pos = base[b] + atomicAdd(&cnt[b], 1);
            if (pos < SLOT)
                bsedge[(size_t)b * SLOT + pos] =
                    make_uint2(((unsigned)(r & 63) << 17) | (unsigned)cols[e],
                               __float_as_uint(vals[e]));
        }
    }
}

// ===========================================================================
// SpMM + in-LDS sort + A/M build (round-17 proven). One block per bucket:
// s = b*SLOT, M = gcur[b]. hist 64 + 1-wave scan + LDS cursor-scatter into
// sL[SLOT], then per 16-lane group: 2 rows serially, branch-free 4-edge
// unroll, edges from LDS; gather fbf8 from global; a/m bf16 -> ambf.
// ===========================================================================
__global__ __launch_bounds__(512) void spmm_sort64_kernel(
    const ushort8_t* __restrict__ fbf8,
    const int* __restrict__ gcur,
    const uint2* __restrict__ bsedge,
    unsigned char* __restrict__ ambf, int N)
{
    __shared__ uint2 sL[SLOT];       // 16KB
    __shared__ int cnt[64];
    __shared__ int base[65];

    const int t = threadIdx.x;
    const int b = blockIdx.x;        // 64-row bucket
    const int s = b * SLOT;
    int M = gcur[b]; if (M > SLOT) M = SLOT;
    const int e = s + M;

    if (t < 64) cnt[t] = 0;
    __syncthreads();
    for (int j = s + t; j < e; j += 512)
        atomicAdd(&cnt[bsedge[j].x >> 17], 1);
    __syncthreads();
    if (t < 64) {
        int c = cnt[t];
        int v = c;
        #pragma unroll
        for (int off = 1; off < 64; off <<= 1) {
            int y = __shfl_up(v, off, 64);
            if (t >= off) v += y;
        }
        base[t] = v - c;
        if (t == 63) base[64] = v;   // M
        cnt[t] = 0;
    }
    __syncthreads();

    const int g = t >> 4;    // 0..31 row group
    const int l = t & 15;    // col group: cols [8l, 8l+8)
    const int row0 = b << 6;

    for (int j = s + t; j < e; j += 512) {
        uint2 ed = bsedge[j];
        int rl = ed.x >> 17;
        int p = atomicAdd(&cnt[rl], 1);
        sL[base[rl] + p] = make_uint2(ed.x & 0x1FFFFu, ed.y);
    }
    __syncthreads();

    #pragma unroll
    for (int rr = 0; rr < 2; ++rr) {
        int r6 = g + rr * 32;
        int row = row0 + r6;
        if (row >= N) continue;
        int j  = base[r6];
        int j1 = base[r6 + 1];
        float acc[8] = {};
        for (; j + 3 < j1; j += 4) {
            uint2 e0 = sL[j],     e1 = sL[j + 1];
            uint2 e2 = sL[j + 2], e3 = sL[j + 3];
            ushort8_t f0 = fbf8[(size_t)e0.x * 16 + l];
            ushort8_t f1 = fbf8[(size_t)e1.x * 16 + l];
            ushort8_t f2 = fbf8[(size_t)e2.x * 16 + l];
            ushort8_t f3 = fbf8[(size_t)e3.x * 16 + l];
            float v0 = __uint_as_float(e0.y), v1 = __uint_as_float(e1.y);
            float v2 = __uint_as_float(e2.y), v3 = __uint_as_float(e3.y);
            #pragma unroll
            for (int q = 0; q < 8; ++q) {
                acc[q] = fmaf(v0, bf2f(f0[q]), acc[q]);
                acc[q] = fmaf(v1, bf2f(f1[q]), acc[q]);
                acc[q] = fmaf(v2, bf2f(f2[q]), acc[q]);
                acc[q] = fmaf(v3, bf2f(f3[q]), acc[q]);
            }
        }
        for (; j < j1; ++j) {
            uint2 e0 = sL[j];
            float v = __uint_as_float(e0.y);
            ushort8_t f0 = fbf8[(size_t)e0.x * 16 + l];
            #pragma unroll
            for (int q = 0; q < 8; ++q) acc[q] = fmaf(v, bf2f(f0[q]), acc[q]);
        }

        ushort8_t fown = fbf8[(size_t)row * 16 + l];
        ushort8_t av, mv;
        #pragma unroll
        for (int q = 0; q < 8; ++q) {
            float f = bf2f(fown[q]);
            av[q] = f2bf(f + acc[q]);
            mv[q] = f2bf(f * acc[q]);
        }
        int swz = (row & 7) << 4;
        unsigned char* rowp = ambf + (size_t)row * 512;
        *(ushort8_t*)(rowp + ((16 * l) ^ swz))       = av;
        *(ushort8_t*)(rowp + 256 + ((16 * l) ^ swz)) = mv;
    }
}

// ===========================================================================
// MFMA fused GEMM (round-4 proven): stage = 32KB linear copy of ambf tile.
// ===========================================================================
__global__ __launch_bounds__(256) void mfma_gemm2_kernel(
    const unsigned char* __restrict__ ambf,
    const unsigned short* __restrict__ WT,
    const float* __restrict__ b1, const float* __restrict__ b2,
    float* __restrict__ out, int N)
{
    __shared__ __align__(16) unsigned char am_raw[64 * 512];

    const int tid = threadIdx.x;
    const int block0 = blockIdx.x * BM;

    const short8* src = (const short8*)(ambf + (size_t)block0 * 512);
    short8* dst = (short8*)am_raw;
    #pragma unroll
    for (int it = 0; it < 8; ++it) {
        int idx = tid + it * 256;
        dst[idx] = src[idx];
    }
    __syncthreads();

    const int lane = tid & 63;
    const int w    = tid >> 6;
    const int wr   = w >> 1;
    const int wc   = w & 1;
    const int l15  = lane & 15;
    const int lk   = lane >> 4;
    const int rswz = (l15 & 7) << 4;

    f32x4 acc[2][4] = {};

    const char* WTc = (const char*)WT;
    const unsigned char* arow0 = am_raw + (wr * 32 + l15) * 512;
    const unsigned char* arow1 = arow0 + 16 * 512;

    #pragma unroll
    for (int ks = 0; ks < 8; ++ks) {
        int kbyte = ks * 64 + lk * 16;
        int akoff = kbyte ^ rswz;
        short8 a0 = *(const short8*)(arow0 + akoff);
        short8 a1 = *(const short8*)(arow1 + akoff);
        short8 bfr[4];
        #pragma unroll
        for (int nc = 0; nc < 4; ++nc) {
            int col = wc * 64 + nc * 16 + l15;
            bfr[nc] = *(const short8*)(WTc + col * 512 + kbyte);
        }
        #pragma unroll
        for (int nc = 0; nc < 4; ++nc) {
            acc[0][nc] = __builtin_amdgcn_mfma_f32_16x16x32_bf16(a0, bfr[nc], acc[0][nc], 0, 0, 0);
            acc[1][nc] = __builtin_amdgcn_mfma_f32_16x16x32_bf16(a1, bfr[nc], acc[1][nc], 0, 0, 0);
        }
    }

    #pragma unroll
    for (int nc = 0; nc < 4; ++nc) {
        int col = wc * 64 + nc * 16 + l15;
        float bias = b1[col] + b2[col];
        #pragma unroll
        for (int mr = 0; mr < 2; ++mr) {
            int rbase = block0 + wr * 32 + mr * 16 + lk * 4;
            #pragma unroll
            for (int r = 0; r < 4; ++r) {
                int row = rbase + r;
                if (row < N) {
                    float v = acc[mr][nc][r] + bias;
                    out[row * 128 + col] = (v >= 0.f) ? v : 0.01f * v;
                }
            }
        }
    }
}

// ===========================================================================
// Tier-2 CSR kernels (round-3, proven)
// ===========================================================================
__global__ __launch_bounds__(256) void hist_kernel(
    const int* __restrict__ rows, int* __restrict__ counts, int E)
{
    int e = blockIdx.x * 256 + threadIdx.x;
    if (e < E) atomicAdd(&counts[rows[e]], 1);
}

__global__ __launch_bounds__(256) void scan_pass1(
    const int* __restrict__ counts, int* __restrict__ btot, int N)
{
    int tid = threadIdx.x;
    int i = blockIdx.x * 1024 + tid * 4;
    int s = 0;
    if (i + 3 < N) {
        int4 v = *(const int4*)(counts + i);
        s = v.x + v.y + v.z + v.w;
    } else {
        for (int q = 0; q < 4; ++q) if (i + q < N) s += counts[i + q];
    }
    #pragma unroll
    for (int off = 32; off >= 1; off >>= 1) s += __shfl_down(s, off, 64);
    __shared__ int ws[4];
    if ((tid & 63) == 0) ws[tid >> 6] = s;
    __syncthreads();
    if (tid == 0) btot[blockIdx.x] = ws[0] + ws[1] + ws[2] + ws[3];
}

__global__ __launch_bounds__(1024) void scan_pass2(
    const int* __restrict__ btot, int* __restrict__ boff, int nb)
{
    __shared__ int wsum[16];
    int tid = threadIdx.x, lane = tid & 63, wid = tid >> 6;
    int x = (tid < nb) ? btot[tid] : 0;
    int v = x;
    #pragma unroll
    for (int off = 1; off < 64; off <<= 1) {
        int y = __shfl_up(v, off, 64);
        if (lane >= off) v += y;
    }
    if (lane == 63) wsum[wid] = v;
    __syncthreads();
    if (wid == 0 && lane < 16) {
        int s = wsum[lane];
        #pragma unroll
        for (int off = 1; off < 16; off <<= 1) {
            int y = __shfl_up(s, off, 64);
            if (lane >= off) s += y;
        }
        wsum[lane] = s;
    }
    __syncthreads();
    int wexcl = wid ? wsum[wid - 1] : 0;
    if (tid < nb) boff[tid] = wexcl + v - x;
}

__global__ __launch_bounds__(256) void scan_pass3(
    int* __restrict__ row_start, int* __restrict__ cursor,
    const int* __restrict__ boff, int N, int E)
{
    int tid = threadIdx.x;
    int base = blockIdx.x * 1024 + tid * 4;
    int c0 = 0, c1 = 0, c2 = 0, c3 = 0;
    if (base + 3 < N) {
        int4 v = *(const int4*)(row_start + base);
        c0 = v.x; c1 = v.y; c2 = v.z; c3 = v.w;
    } else {
        if (base + 0 < N) c0 = row_start[base + 0];
        if (base + 1 < N) c1 = row_start[base + 1];
        if (base + 2 < N) c2 = row_start[base + 2];
        if (base + 3 < N) c3 = row_start[base + 3];
    }
    int s0 = c0, s1 = s0 + c1, s2 = s1 + c2, s3 = s2 + c3;
    int lane = tid & 63, wid = tid >> 6;
    int v = s3;
    #pragma unroll
    for (int off = 1; off < 64; off <<= 1) {
        int y = __shfl_up(v, off, 64);
        if (lane >= off) v += y;
    }
    __shared__ int ws[4];
    if (lane == 63) ws[wid] = v;
    __syncthreads();
    int wexcl = 0;
    for (int q = 0; q < wid; ++q) wexcl += ws[q];
    int texcl = wexcl + (v - s3) + boff[blockIdx.x];
    int e0 = texcl, e1 = texcl + s0, e2 = texcl + s1, e3 = texcl + s2;
    if (base + 0 < N) { row_start[base + 0] = e0; cursor[base + 0] = e0; }
    if (base + 1 < N) { row_start[base + 1] = e1; cursor[base + 1] = e1; }
    if (base + 2 < N) { row_start[base + 2] = e2; cursor[base + 2] = e2; }
    if (base + 3 < N) { row_start[base + 3] = e3; cursor[base + 3] = e3; }
    if (blockIdx.x == 0 && tid == 0) row_start[N] = E;
}

__global__ __launch_bounds__(256) void scatter_sort_kernel(
    const int* __restrict__ rows, const int* __restrict__ cols,
    const float* __restrict__ vals, int* __restrict__ cursor,
    uint2* __restrict__ sedge, int E)
{
    int e = blockIdx.x * 256 + threadIdx.x;
    if (e < E) {
        int r = rows[e];
        int p = atomicAdd(&cursor[r], 1);
        sedge[p] = make_uint2((unsigned)cols[e], __float_as_uint(vals[e]));
    }
}

__global__ __launch_bounds__(256) void spmm_kernel(
    const float2* __restrict__ feat2,
    const int* __restrict__ row_start,
    const uint2* __restrict__ sedge,
    float2* __restrict__ h2, int N)
{
    int gw = (blockIdx.x * 256 + threadIdx.x) >> 6;
    int lane = threadIdx.x & 63;
    if (gw >= N) return;
    int s = row_start[gw];
    int e = row_start[gw + 1];
    float2 acc = make_float2(0.f, 0.f);
    int j = s;
    for (; j + 1 < e; j += 2) {
        uint2 e0 = sedge[j], e1 = sedge[j + 1];
        float v0 = __uint_as_float(e0.y), v1 = __uint_as_float(e1.y);
        float2 f0 = feat2[(size_t)e0.x * 64 + lane];
        float2 f1 = feat2[(size_t)e1.x * 64 + lane];
        acc.x = fmaf(v0, f0.x, acc.x);
        acc.y = fmaf(v0, f0.y, acc.y);
        acc.x = fmaf(v1, f1.x, acc.x);
        acc.y = fmaf(v1, f1.y, acc.y);
    }
    if (j < e) {
        uint2 e0 = sedge[j];
        float v = __uint_as_float(e0.y);
        float2 f = feat2[(size_t)e0.x * 64 + lane];
        acc.x = fmaf(v, f.x, acc.x);
        acc.y = fmaf(v, f.y, acc.y);
    }
    h2[(size_t)gw * 64 + lane] = acc;
}

__global__ __launch_bounds__(256) void mfma_gemm_kernel(
    const float4* __restrict__ feat4, const float4* __restrict__ h4,
    const unsigned short* __restrict__ WT,
    const float* __restrict__ b1, const float* __restrict__ b2,
    float* __restrict__ out, int N)
{
    __shared__ __align__(16) unsigned char am_raw[64 * 512];
    const int tid = threadIdx.x;
    const int block0 = blockIdx.x * BM;
    #pragma unroll
    for (int it = 0; it < 8; ++it) {
        int idx  = tid + it * 256;
        int node = idx >> 5;
        int p    = idx & 31;
        int g    = block0 + node;
        float4 fv = make_float4(0.f, 0.f, 0.f, 0.f);
        float4 hv = make_float4(0.f, 0.f, 0.f, 0.f);
        if (g < N) { fv = feat4[g * 32 + p]; hv = h4[g * 32 + p]; }
        ushort4 av = make_ushort4(f2bf(fv.x + hv.x), f2bf(fv.y + hv.y),
                                  f2bf(fv.z + hv.z), f2bf(fv.w + hv.w));
        ushort4 mv = make_ushort4(f2bf(fv.x * hv.x), f2bf(fv.y * hv.y),
                                  f2bf(fv.z * hv.z), f2bf(fv.w * hv.w));
        int swz = (node & 7) << 4;
        *(ushort4*)(am_raw + node * 512 + ((p * 8) ^ swz))       = av;
        *(ushort4*)(am_raw + node * 512 + ((256 + p * 8) ^ swz)) = mv;
    }
    __syncthreads();
    const int lane = tid & 63;
    const int w    = tid >> 6;
    const int wr   = w >> 1;
    const int wc   = w & 1;
    const int l15  = lane & 15;
    const int lk   = lane >> 4;
    const int rswz = (l15 & 7) << 4;
    f32x4 acc[2][4] = {};
    const char* WTc = (const char*)WT;
    const unsigned char* arow0 = am_raw + (wr * 32 + l15) * 512;
    const unsigned char* arow1 = arow0 + 16 * 512;
    #pragma unroll
    for (int ks = 0; ks < 8; ++ks) {
        int kbyte = ks * 64 + lk * 16;
        int akoff = kbyte ^ rswz;
        short8 a0 = *(const short8*)(arow0 + akoff);
        short8 a1 = *(const short8*)(arow1 + akoff);
        short8 bfr[4];
        #pragma unroll
        for (int nc = 0; nc < 4; ++nc) {
            int col = wc * 64 + nc * 16 + l15;
            bfr[nc] = *(const short8*)(WTc + col * 512 + kbyte);
        }
        #pragma unroll
        for (int nc = 0; nc < 4; ++nc) {
            acc[0][nc] = __builtin_amdgcn_mfma_f32_16x16x32_bf16(a0, bfr[nc], acc[0][nc], 0, 0, 0);
            acc[1][nc] = __builtin_amdgcn_mfma_f32_16x16x32_bf16(a1, bfr[nc], acc[1][nc], 0, 0, 0);
        }
    }
    #pragma unroll
    for (int nc = 0; nc < 4; ++nc) {
        int col = wc * 64 + nc * 16 + l15;
        float bias = b1[col] + b2[col];
        #pragma unroll
        for (int mr = 0; mr < 2; ++mr) {
            int rbase = block0 + wr * 32 + mr * 16 + lk * 4;
            #pragma unroll
            for (int r = 0; r < 4; ++r) {
                int row = rbase + r;
                if (row < N) {
                    float v = acc[mr][nc][r] + bias;
                    out[row * 128 + col] = (v >= 0.f) ? v : 0.01f * v;
                }
            }
        }
    }
}

// ===========================================================================
// Tier-3: atomic scatter + fp32 VALU GEMM
// ===========================================================================
__global__ __launch_bounds__(256) void edge_scatter_kernel(
    const float4* __restrict__ feat4, const int* __restrict__ rows,
    const int* __restrict__ cols, const float* __restrict__ vals,
    float* __restrict__ h, int E)
{
    int idx = blockIdx.x * 256 + threadIdx.x;
    if (idx >= E * 32) return;
    int e = idx >> 5;
    int p = idx & 31;
    int r = rows[e];
    int c = cols[e];
    float v = vals[e];
    float4 f = feat4[c * 32 + p];
    float* hr = h + (long long)r * D + p * 4;
    unsafeAtomicAdd(hr + 0, v * f.x);
    unsafeAtomicAdd(hr + 1, v * f.y);
    unsafeAtomicAdd(hr + 2, v * f.z);
    unsafeAtomicAdd(hr + 3, v * f.w);
}

__global__ __launch_bounds__(256) void fused_gemm_kernel(
    const float* __restrict__ feat, const float* __restrict__ h,
    const float* __restrict__ W1, const float* __restrict__ b1,
    const float* __restrict__ W2, const float* __restrict__ b2,
    float* __restrict__ out, int N)
{
    __shared__ float a_lds[BM][D];
    __shared__ float m_lds[BM][D];
    const int tid = threadIdx.x;
    const int block0 = blockIdx.x * BM;
    const float4* feat4 = (const float4*)feat;
    const float4* h4    = (const float4*)h;
    #pragma unroll
    for (int it = 0; it < 8; ++it) {
        int idx  = tid + it * 256;
        int node = idx >> 5;
        int p    = idx & 31;
        int gnode = block0 + node;
        float4 fv = make_float4(0.f, 0.f, 0.f, 0.f);
        float4 hv = make_float4(0.f, 0.f, 0.f, 0.f);
        if (gnode < N) { fv = feat4[gnode * 32 + p]; hv = h4[gnode * 32 + p]; }
        float4 av = make_float4(fv.x + hv.x, fv.y + hv.y, fv.z + hv.z, fv.w + hv.w);
        float4 mv = make_float4(fv.x * hv.x, fv.y * hv.y, fv.z * hv.z, fv.w * hv.w);
        *(float4*)&a_lds[node][p * 4] = av;
        *(float4*)&m_lds[node][p * 4] = mv;
    }
    __syncthreads();
    const int c = tid & 31;
    const int g = tid >> 5;
    float acc[8][4] = {};
    const float4* W1v = (const float4*)W1;
    const float4* W2v = (const float4*)W2;
    for (int k = 0; k < D; ++k) {
        float4 w1 = W1v[k * 32 + c];
        float4 w2 = W2v[k * 32 + c];
        #pragma unroll
        for (int t = 0; t < 8; ++t) {
            float av = a_lds[g + 8 * t][k];
            float mv = m_lds[g + 8 * t][k];
            acc[t][0] = fmaf(av, w1.x, fmaf(mv, w2.x, acc[t][0]));
            acc[t][1] = fmaf(av, w1.y, fmaf(mv, w2.y, acc[t][1]));
            acc[t][2] = fmaf(av, w1.z, fmaf(mv, w2.z, acc[t][2]));
            acc[t][3] = fmaf(av, w1.w, fmaf(mv, w2.w, acc[t][3]));
        }
    }
    float4 bb1 = ((const float4*)b1)[c];
    float4 bb2 = ((const float4*)b2)[c];
    const float bx = bb1.x + bb2.x, by = bb1.y + bb2.y;
    const float bz = bb1.z + bb2.z, bw = bb1.w + bb2.w;
    #pragma unroll
    for (int t = 0; t < 8; ++t) {
        int gnode = block0 + g + 8 * t;
        if (gnode >= N) continue;
        float4 o;
        o.x = acc[t][0] + bx; o.y = acc[t][1] + by;
        o.z = acc[t][2] + bz; o.w = acc[t][3] + bw;
        o.x = (o.x >= 0.f) ? o.x : 0.01f * o.x;
        o.y = (o.y >= 0.f) ? o.y : 0.01f * o.y;
        o.z = (o.z >= 0.f) ? o.z : 0.01f * o.z;
        o.w = (o.w >= 0.f) ? o.w : 0.01f * o.w;
        ((float4*)out)[gnode * 32 + c] = o;
    }
}

extern "C" void kernel_launch(void* const* d_in, const int* in_sizes, int n_in,
                              void* d_out, int out_size, void* d_ws, size_t ws_size,
                              hipStream_t stream) {
    const float* feat = (const float*)d_in[0];
    const int*   rows = (const int*)d_in[1];
    const int*   cols = (const int*)d_in[2];
    const float* vals = (const float*)d_in[3];
    const float* W1   = (const float*)d_in[4];
    const float* b1   = (const float*)d_in[5];
    const float* W2   = (const float*)d_in[6];
    const float* b2   = (const float*)d_in[7];

    const int N = in_sizes[0] / D;
    const int E = in_sizes[1];
    float* out = (float*)d_out;

    const int NBK  = (N + 63) >> 6;           // 64-row buckets (1563)
    const int Npad = NBK << 6;

    // --- Tier-1: ambf | featbf | WT | bsedge(padded) | gcur
    size_t off = 0;
    unsigned char* ambf = (unsigned char*)d_ws;                    off += (size_t)Npad * 512;
    unsigned short* featbf = (unsigned short*)((char*)d_ws + off); off += (size_t)N * D * 2;
    off = (off + 15) & ~(size_t)15;
    unsigned short* WT = (unsigned short*)((char*)d_ws + off);     off += 128 * 256 * 2;
    off = (off + 15) & ~(size_t)15;
    uint2* bsedge = (uint2*)((char*)d_ws + off);                   off += (size_t)NBK * SLOT * 8;
    int* gcur = (int*)((char*)d_ws + off);                         off += (size_t)NBK * 4;
    size_t need1 = off;

    if (ws_size >= need1 && NBK <= 2048 && N <= (1 << 17)) {
        hipMemsetAsync(gcur, 0, (size_t)NBK * sizeof(int), stream);
        prep_kernel<<<1024, 256, 0, stream>>>(
            (const float4*)feat, (ushort4*)featbf, N * 32, W1, W2, WT);
        bucket_scatter_kernel<<<(E + 2047) / 2048, 256, 0, stream>>>(
            rows, cols, vals, gcur, bsedge, E, NBK);
        spmm_sort64_kernel<<<NBK, 512, 0, stream>>>(
            (const ushort8_t*)featbf, gcur, bsedge, ambf, N);
        mfma_gemm2_kernel<<<(N + BM - 1) / BM, 256, 0, stream>>>(
            ambf, WT, b1, b2, out, N);
        return;
    }

    // --- Tier-2: round-3 fp32 CSR path ---
    const int NB = (N + 1023) / 1024;
    off = 0;
    float* h = (float*)d_ws;                           off += (size_t)N * D * 4;
    int* row_start2 = (int*)((char*)d_ws + off);       off += (size_t)(N + 1) * 4;
    int* cursor2    = (int*)((char*)d_ws + off);       off += (size_t)N * 4;
    off = (off + 15) & ~(size_t)15;
    uint2* sedge2   = (uint2*)((char*)d_ws + off);     off += (size_t)E * 8;
    off = (off + 15) & ~(size_t)15;
    unsigned short* WT2 = (unsigned short*)((char*)d_ws + off); off += 128 * 256 * 2;
    int* btot2 = (int*)((char*)d_ws + off);            off += (size_t)NB * 4;
    int* boff2 = (int*)((char*)d_ws + off);            off += (size_t)NB * 4;
    size_t need2 = off;

    if (ws_size >= need2 && NB <= 1024) {
        hipMemsetAsync(row_start2, 0, (size_t)(N + 1) * sizeof(int), stream);
        wconv_kernel<<<128, 256, 0, stream>>>(W1, W2, WT2);
        hist_kernel<<<(E + 255) / 256, 256, 0, stream>>>(rows, row_start2, E);
        scan_pass1<<<NB, 256, 0, stream>>>(row_start2, btot2, N);
        scan_pass2<<<1, 1024, 0, stream>>>(btot2, boff2, NB);
        scan_pass3<<<NB, 256, 0, stream>>>(row_start2, cursor2, boff2, N, E);
        scatter_sort_kernel<<<(E + 255) / 256, 256, 0, stream>>>(
            rows, cols, vals, cursor2, sedge2, E);
        spmm_kernel<<<(N * 64 + 255) / 256, 256, 0, stream>>>(
            (const float2*)feat, row_start2, sedge2, (float2*)h, N);
        mfma_gemm_kernel<<<(N + BM - 1) / BM, 256, 0, stream>>>(
            (const float4*)feat, (const float4*)h, WT2, b1, b2, out, N);
        return;
    }

    // --- Tier-3: atomic scatter + VALU GEMM ---
    size_t hbytes = (size_t)N * D * sizeof(float);
    float* hh = (ws_size >= hbytes) ? (float*)d_ws : out;
    hipMemsetAsync(hh, 0, hbytes, stream);
    edge_scatter_kernel<<<((size_t)E * 32 + 255) / 256, 256, 0, stream>>>(
        (const float4*)feat, rows, cols, vals, hh, E);
    fused_gemm_kernel<<<(N + BM - 1) / BM, 256, 0, stream>>>(
        feat, hh, W1, b1, W2, b2, out, N);
}

// Round 20
// 165.432 us; speedup vs baseline: 1.0815x; 1.0815x over previous
//
#include <hip/hip_runtime.h>

#define D 128
#define BM 64
#define SLOT 2048

typedef short short8 __attribute__((ext_vector_type(8)));
typedef unsigned short ushort8_t __attribute__((ext_vector_type(8)));
typedef float f32x4 __attribute__((ext_vector_type(4)));

__device__ __forceinline__ unsigned short f2bf(float x) {
    unsigned u = __float_as_uint(x);
    unsigned r = (u + 0x7fffu + ((u >> 16) & 1u)) >> 16;   // RNE
    return (unsigned short)r;
}
__device__ __forceinline__ float bf2f(unsigned short u) {
    return __uint_as_float(((unsigned)u) << 16);
}

// ===========================================================================
// PREP: features fp32->bf16 + WT build. Grid-stride; launched at 1024 blocks.
// ===========================================================================
__global__ __launch_bounds__(256) void prep_kernel(
    const float4* __restrict__ feat4, ushort4* __restrict__ fbf4, int nf4,
    const float* __restrict__ W1, const float* __restrict__ W2,
    unsigned short* __restrict__ WT)
{
    const int t = threadIdx.x;
    const int b = blockIdx.x;
    const int stride = gridDim.x * 256;

    for (int i = b * 256 + t; i < nf4; i += stride) {
        float4 v = feat4[i];
        fbf4[i] = make_ushort4(f2bf(v.x), f2bf(v.y), f2bf(v.z), f2bf(v.w));
    }

    if (b < 128) {
        int idx = b * 256 + t;
        int c = idx & 127;
        int k = idx >> 7;
        float w = (k < 128) ? W1[k * 128 + c] : W2[(k - 128) * 128 + c];
        WT[c * 256 + k] = f2bf(w);
    }
}

// ===========================================================================
// Standalone fconv/wconv (fallback tiers)
// ===========================================================================
__global__ __launch_bounds__(256) void fconv_kernel(
    const float4* __restrict__ feat4, ushort4* __restrict__ fbf4, int total)
{
    int i = blockIdx.x * 256 + threadIdx.x;
    if (i < total) {
        float4 v = feat4[i];
        fbf4[i] = make_ushort4(f2bf(v.x), f2bf(v.y), f2bf(v.z), f2bf(v.w));
    }
}

__global__ __launch_bounds__(256) void wconv_kernel(
    const float* __restrict__ W1, const float* __restrict__ W2,
    unsigned short* __restrict__ WT)
{
    int idx = blockIdx.x * 256 + threadIdx.x;
    int c = idx & 127;
    int k = idx >> 7;
    float w = (k < 128) ? W1[k * 128 + c] : W2[(k - 128) * 128 + c];
    WT[c * 256 + k] = f2bf(w);
}

// ===========================================================================
// Bucket scatter into PADDED slots (round-17 proven, EPB=4096):
// bucket b owns bsedge[b*SLOT .. +SLOT); gcur[b] (zeroed) = cursor/count.
// Edge key = (r&63)<<17 | col (needs N <= 2^17). 64-row buckets.
// ===========================================================================
__global__ __launch_bounds__(256) void bucket_scatter_kernel(
    const int* __restrict__ rows, const int* __restrict__ cols,
    const float* __restrict__ vals, int* __restrict__ gcur,
    uint2* __restrict__ bsedge, int E, int nb)
{
    __shared__ int cnt[2048];
    __shared__ int base[2048];
    int t = threadIdx.x;
    int e0 = blockIdx.x * 4096;
    for (int i = t; i < nb; i += 256) cnt[i] = 0;
    __syncthreads();
    #pragma unroll
    for (int q = 0; q < 16; ++q) {
        int e = e0 + t + q * 256;
        if (e < E) atomicAdd(&cnt[rows[e] >> 6], 1);
    }
    __syncthreads();
    for (int i = t; i < nb; i += 256) {
        int c = cnt[i];
        if (c) { base[i] = atomicAdd(&gcur[i], c); cnt[i] = 0; }
    }
    __syncthreads();
    #pragma unroll
    for (int q = 0; q < 16; ++q) {
        int e = e0 + t + q * 256;
        if (e < E) {
            int r = rows[e];
            int b = r >> 6;
            int pos = base[b] + atomicAdd(&cnt[b], 1);
            if (pos < SLOT)
                bsedge[(size_t)b * SLOT + pos] =
                    make_uint2(((unsigned)(r & 63) << 17) | (unsigned)cols[e],
                               __float_as_uint(vals[e]));
        }
    }
}

// ===========================================================================
// SpMM + in-LDS sort + A/M build (round-17 proven). One block per bucket:
// s = b*SLOT, M = gcur[b]. hist 64 + 1-wave scan + LDS cursor-scatter into
// sL[SLOT], then per 16-lane group: 2 rows serially, branch-free 4-edge
// unroll, edges from LDS; gather fbf8 from global; a/m bf16 -> ambf.
// ===========================================================================
__global__ __launch_bounds__(512) void spmm_sort64_kernel(
    const ushort8_t* __restrict__ fbf8,
    const int* __restrict__ gcur,
    const uint2* __restrict__ bsedge,
    unsigned char* __restrict__ ambf, int N)
{
    __shared__ uint2 sL[SLOT];       // 16KB
    __shared__ int cnt[64];
    __shared__ int base[65];

    const int t = threadIdx.x;
    const int b = blockIdx.x;        // 64-row bucket
    const int s = b * SLOT;
    int M = gcur[b]; if (M > SLOT) M = SLOT;
    const int e = s + M;

    if (t < 64) cnt[t] = 0;
    __syncthreads();
    for (int j = s + t; j < e; j += 512)
        atomicAdd(&cnt[bsedge[j].x >> 17], 1);
    __syncthreads();
    if (t < 64) {
        int c = cnt[t];
        int v = c;
        #pragma unroll
        for (int off = 1; off < 64; off <<= 1) {
            int y = __shfl_up(v, off, 64);
            if (t >= off) v += y;
        }
        base[t] = v - c;
        if (t == 63) base[64] = v;   // M
        cnt[t] = 0;
    }
    __syncthreads();

    const int g = t >> 4;    // 0..31 row group
    const int l = t & 15;    // col group: cols [8l, 8l+8)
    const int row0 = b << 6;

    for (int j = s + t; j < e; j += 512) {
        uint2 ed = bsedge[j];
        int rl = ed.x >> 17;
        int p = atomicAdd(&cnt[rl], 1);
        sL[base[rl] + p] = make_uint2(ed.x & 0x1FFFFu, ed.y);
    }
    __syncthreads();

    #pragma unroll
    for (int rr = 0; rr < 2; ++rr) {
        int r6 = g + rr * 32;
        int row = row0 + r6;
        if (row >= N) continue;
        int j  = base[r6];
        int j1 = base[r6 + 1];
        float acc[8] = {};
        for (; j + 3 < j1; j += 4) {
            uint2 e0 = sL[j],     e1 = sL[j + 1];
            uint2 e2 = sL[j + 2], e3 = sL[j + 3];
            ushort8_t f0 = fbf8[(size_t)e0.x * 16 + l];
            ushort8_t f1 = fbf8[(size_t)e1.x * 16 + l];
            ushort8_t f2 = fbf8[(size_t)e2.x * 16 + l];
            ushort8_t f3 = fbf8[(size_t)e3.x * 16 + l];
            float v0 = __uint_as_float(e0.y), v1 = __uint_as_float(e1.y);
            float v2 = __uint_as_float(e2.y), v3 = __uint_as_float(e3.y);
            #pragma unroll
            for (int q = 0; q < 8; ++q) {
                acc[q] = fmaf(v0, bf2f(f0[q]), acc[q]);
                acc[q] = fmaf(v1, bf2f(f1[q]), acc[q]);
                acc[q] = fmaf(v2, bf2f(f2[q]), acc[q]);
                acc[q] = fmaf(v3, bf2f(f3[q]), acc[q]);
            }
        }
        for (; j < j1; ++j) {
            uint2 e0 = sL[j];
            float v = __uint_as_float(e0.y);
            ushort8_t f0 = fbf8[(size_t)e0.x * 16 + l];
            #pragma unroll
            for (int q = 0; q < 8; ++q) acc[q] = fmaf(v, bf2f(f0[q]), acc[q]);
        }

        ushort8_t fown = fbf8[(size_t)row * 16 + l];
        ushort8_t av, mv;
        #pragma unroll
        for (int q = 0; q < 8; ++q) {
            float f = bf2f(fown[q]);
            av[q] = f2bf(f + acc[q]);
            mv[q] = f2bf(f * acc[q]);
        }
        int swz = (row & 7) << 4;
        unsigned char* rowp = ambf + (size_t)row * 512;
        *(ushort8_t*)(rowp + ((16 * l) ^ swz))       = av;
        *(ushort8_t*)(rowp + 256 + ((16 * l) ^ swz)) = mv;
    }
}

// ===========================================================================
// MFMA fused GEMM (round-4 proven): stage = 32KB linear copy of ambf tile.
// ===========================================================================
__global__ __launch_bounds__(256) void mfma_gemm2_kernel(
    const unsigned char* __restrict__ ambf,
    const unsigned short* __restrict__ WT,
    const float* __restrict__ b1, const float* __restrict__ b2,
    float* __restrict__ out, int N)
{
    __shared__ __align__(16) unsigned char am_raw[64 * 512];

    const int tid = threadIdx.x;
    const int block0 = blockIdx.x * BM;

    const short8* src = (const short8*)(ambf + (size_t)block0 * 512);
    short8* dst = (short8*)am_raw;
    #pragma unroll
    for (int it = 0; it < 8; ++it) {
        int idx = tid + it * 256;
        dst[idx] = src[idx];
    }
    __syncthreads();

    const int lane = tid & 63;
    const int w    = tid >> 6;
    const int wr   = w >> 1;
    const int wc   = w & 1;
    const int l15  = lane & 15;
    const int lk   = lane >> 4;
    const int rswz = (l15 & 7) << 4;

    f32x4 acc[2][4] = {};

    const char* WTc = (const char*)WT;
    const unsigned char* arow0 = am_raw + (wr * 32 + l15) * 512;
    const unsigned char* arow1 = arow0 + 16 * 512;

    #pragma unroll
    for (int ks = 0; ks < 8; ++ks) {
        int kbyte = ks * 64 + lk * 16;
        int akoff = kbyte ^ rswz;
        short8 a0 = *(const short8*)(arow0 + akoff);
        short8 a1 = *(const short8*)(arow1 + akoff);
        short8 bfr[4];
        #pragma unroll
        for (int nc = 0; nc < 4; ++nc) {
            int col = wc * 64 + nc * 16 + l15;
            bfr[nc] = *(const short8*)(WTc + col * 512 + kbyte);
        }
        #pragma unroll
        for (int nc = 0; nc < 4; ++nc) {
            acc[0][nc] = __builtin_amdgcn_mfma_f32_16x16x32_bf16(a0, bfr[nc], acc[0][nc], 0, 0, 0);
            acc[1][nc] = __builtin_amdgcn_mfma_f32_16x16x32_bf16(a1, bfr[nc], acc[1][nc], 0, 0, 0);
        }
    }

    #pragma unroll
    for (int nc = 0; nc < 4; ++nc) {
        int col = wc * 64 + nc * 16 + l15;
        float bias = b1[col] + b2[col];
        #pragma unroll
        for (int mr = 0; mr < 2; ++mr) {
            int rbase = block0 + wr * 32 + mr * 16 + lk * 4;
            #pragma unroll
            for (int r = 0; r < 4; ++r) {
                int row = rbase + r;
                if (row < N) {
                    float v = acc[mr][nc][r] + bias;
                    out[row * 128 + col] = (v >= 0.f) ? v : 0.01f * v;
                }
            }
        }
    }
}

// ===========================================================================
// Tier-2 CSR kernels (round-3, proven)
// ===========================================================================
__global__ __launch_bounds__(256) void hist_kernel(
    const int* __restrict__ rows, int* __restrict__ counts, int E)
{
    int e = blockIdx.x * 256 + threadIdx.x;
    if (e < E) atomicAdd(&counts[rows[e]], 1);
}

__global__ __launch_bounds__(256) void scan_pass1(
    const int* __restrict__ counts, int* __restrict__ btot, int N)
{
    int tid = threadIdx.x;
    int i = blockIdx.x * 1024 + tid * 4;
    int s = 0;
    if (i + 3 < N) {
        int4 v = *(const int4*)(counts + i);
        s = v.x + v.y + v.z + v.w;
    } else {
        for (int q = 0; q < 4; ++q) if (i + q < N) s += counts[i + q];
    }
    #pragma unroll
    for (int off = 32; off >= 1; off >>= 1) s += __shfl_down(s, off, 64);
    __shared__ int ws[4];
    if ((tid & 63) == 0) ws[tid >> 6] = s;
    __syncthreads();
    if (tid == 0) btot[blockIdx.x] = ws[0] + ws[1] + ws[2] + ws[3];
}

__global__ __launch_bounds__(1024) void scan_pass2(
    const int* __restrict__ btot, int* __restrict__ boff, int nb)
{
    __shared__ int wsum[16];
    int tid = threadIdx.x, lane = tid & 63, wid = tid >> 6;
    int x = (tid < nb) ? btot[tid] : 0;
    int v = x;
    #pragma unroll
    for (int off = 1; off < 64; off <<= 1) {
        int y = __shfl_up(v, off, 64);
        if (lane >= off) v += y;
    }
    if (lane == 63) wsum[wid] = v;
    __syncthreads();
    if (wid == 0 && lane < 16) {
        int s = wsum[lane];
        #pragma unroll
        for (int off = 1; off < 16; off <<= 1) {
            int y = __shfl_up(s, off, 64);
            if (lane >= off) s += y;
        }
        wsum[lane] = s;
    }
    __syncthreads();
    int wexcl = wid ? wsum[wid - 1] : 0;
    if (tid < nb) boff[tid] = wexcl + v - x;
}

__global__ __launch_bounds__(256) void scan_pass3(
    int* __restrict__ row_start, int* __restrict__ cursor,
    const int* __restrict__ boff, int N, int E)
{
    int tid = threadIdx.x;
    int base = blockIdx.x * 1024 + tid * 4;
    int c0 = 0, c1 = 0, c2 = 0, c3 = 0;
    if (base + 3 < N) {
        int4 v = *(const int4*)(row_start + base);
        c0 = v.x; c1 = v.y; c2 = v.z; c3 = v.w;
    } else {
        if (base + 0 < N) c0 = row_start[base + 0];
        if (base + 1 < N) c1 = row_start[base + 1];
        if (base + 2 < N) c2 = row_start[base + 2];
        if (base + 3 < N) c3 = row_start[base + 3];
    }
    int s0 = c0, s1 = s0 + c1, s2 = s1 + c2, s3 = s2 + c3;
    int lane = tid & 63, wid = tid >> 6;
    int v = s3;
    #pragma unroll
    for (int off = 1; off < 64; off <<= 1) {
        int y = __shfl_up(v, off, 64);
        if (lane >= off) v += y;
    }
    __shared__ int ws[4];
    if (lane == 63) ws[wid] = v;
    __syncthreads();
    int wexcl = 0;
    for (int q = 0; q < wid; ++q) wexcl += ws[q];
    int texcl = wexcl + (v - s3) + boff[blockIdx.x];
    int e0 = texcl, e1 = texcl + s0, e2 = texcl + s1, e3 = texcl + s2;
    if (base + 0 < N) { row_start[base + 0] = e0; cursor[base + 0] = e0; }
    if (base + 1 < N) { row_start[base + 1] = e1; cursor[base + 1] = e1; }
    if (base + 2 < N) { row_start[base + 2] = e2; cursor[base + 2] = e2; }
    if (base + 3 < N) { row_start[base + 3] = e3; cursor[base + 3] = e3; }
    if (blockIdx.x == 0 && tid == 0) row_start[N] = E;
}

__global__ __launch_bounds__(256) void scatter_sort_kernel(
    const int* __restrict__ rows, const int* __restrict__ cols,
    const float* __restrict__ vals, int* __restrict__ cursor,
    uint2* __restrict__ sedge, int E)
{
    int e = blockIdx.x * 256 + threadIdx.x;
    if (e < E) {
        int r = rows[e];
        int p = atomicAdd(&cursor[r], 1);
        sedge[p] = make_uint2((unsigned)cols[e], __float_as_uint(vals[e]));
    }
}

__global__ __launch_bounds__(256) void spmm_kernel(
    const float2* __restrict__ feat2,
    const int* __restrict__ row_start,
    const uint2* __restrict__ sedge,
    float2* __restrict__ h2, int N)
{
    int gw = (blockIdx.x * 256 + threadIdx.x) >> 6;
    int lane = threadIdx.x & 63;
    if (gw >= N) return;
    int s = row_start[gw];
    int e = row_start[gw + 1];
    float2 acc = make_float2(0.f, 0.f);
    int j = s;
    for (; j + 1 < e; j += 2) {
        uint2 e0 = sedge[j], e1 = sedge[j + 1];
        float v0 = __uint_as_float(e0.y), v1 = __uint_as_float(e1.y);
        float2 f0 = feat2[(size_t)e0.x * 64 + lane];
        float2 f1 = feat2[(size_t)e1.x * 64 + lane];
        acc.x = fmaf(v0, f0.x, acc.x);
        acc.y = fmaf(v0, f0.y, acc.y);
        acc.x = fmaf(v1, f1.x, acc.x);
        acc.y = fmaf(v1, f1.y, acc.y);
    }
    if (j < e) {
        uint2 e0 = sedge[j];
        float v = __uint_as_float(e0.y);
        float2 f = feat2[(size_t)e0.x * 64 + lane];
        acc.x = fmaf(v, f.x, acc.x);
        acc.y = fmaf(v, f.y, acc.y);
    }
    h2[(size_t)gw * 64 + lane] = acc;
}

__global__ __launch_bounds__(256) void mfma_gemm_kernel(
    const float4* __restrict__ feat4, const float4* __restrict__ h4,
    const unsigned short* __restrict__ WT,
    const float* __restrict__ b1, const float* __restrict__ b2,
    float* __restrict__ out, int N)
{
    __shared__ __align__(16) unsigned char am_raw[64 * 512];
    const int tid = threadIdx.x;
    const int block0 = blockIdx.x * BM;
    #pragma unroll
    for (int it = 0; it < 8; ++it) {
        int idx  = tid + it * 256;
        int node = idx >> 5;
        int p    = idx & 31;
        int g    = block0 + node;
        float4 fv = make_float4(0.f, 0.f, 0.f, 0.f);
        float4 hv = make_float4(0.f, 0.f, 0.f, 0.f);
        if (g < N) { fv = feat4[g * 32 + p]; hv = h4[g * 32 + p]; }
        ushort4 av = make_ushort4(f2bf(fv.x + hv.x), f2bf(fv.y + hv.y),
                                  f2bf(fv.z + hv.z), f2bf(fv.w + hv.w));
        ushort4 mv = make_ushort4(f2bf(fv.x * hv.x), f2bf(fv.y * hv.y),
                                  f2bf(fv.z * hv.z), f2bf(fv.w * hv.w));
        int swz = (node & 7) << 4;
        *(ushort4*)(am_raw + node * 512 + ((p * 8) ^ swz))       = av;
        *(ushort4*)(am_raw + node * 512 + ((256 + p * 8) ^ swz)) = mv;
    }
    __syncthreads();
    const int lane = tid & 63;
    const int w    = tid >> 6;
    const int wr   = w >> 1;
    const int wc   = w & 1;
    const int l15  = lane & 15;
    const int lk   = lane >> 4;
    const int rswz = (l15 & 7) << 4;
    f32x4 acc[2][4] = {};
    const char* WTc = (const char*)WT;
    const unsigned char* arow0 = am_raw + (wr * 32 + l15) * 512;
    const unsigned char* arow1 = arow0 + 16 * 512;
    #pragma unroll
    for (int ks = 0; ks < 8; ++ks) {
        int kbyte = ks * 64 + lk * 16;
        int akoff = kbyte ^ rswz;
        short8 a0 = *(const short8*)(arow0 + akoff);
        short8 a1 = *(const short8*)(arow1 + akoff);
        short8 bfr[4];
        #pragma unroll
        for (int nc = 0; nc < 4; ++nc) {
            int col = wc * 64 + nc * 16 + l15;
            bfr[nc] = *(const short8*)(WTc + col * 512 + kbyte);
        }
        #pragma unroll
        for (int nc = 0; nc < 4; ++nc) {
            acc[0][nc] = __builtin_amdgcn_mfma_f32_16x16x32_bf16(a0, bfr[nc], acc[0][nc], 0, 0, 0);
            acc[1][nc] = __builtin_amdgcn_mfma_f32_16x16x32_bf16(a1, bfr[nc], acc[1][nc], 0, 0, 0);
        }
    }
    #pragma unroll
    for (int nc = 0; nc < 4; ++nc) {
        int col = wc * 64 + nc * 16 + l15;
        float bias = b1[col] + b2[col];
        #pragma unroll
        for (int mr = 0; mr < 2; ++mr) {
            int rbase = block0 + wr * 32 + mr * 16 + lk * 4;
            #pragma unroll
            for (int r = 0; r < 4; ++r) {
                int row = rbase + r;
                if (row < N) {
                    float v = acc[mr][nc][r] + bias;
                    out[row * 128 + col] = (v >= 0.f) ? v : 0.01f * v;
                }
            }
        }
    }
}

// ===========================================================================
// Tier-3: atomic scatter + fp32 VALU GEMM
// ===========================================================================
__global__ __launch_bounds__(256) void edge_scatter_kernel(
    const float4* __restrict__ feat4, const int* __restrict__ rows,
    const int* __restrict__ cols, const float* __restrict__ vals,
    float* __restrict__ h, int E)
{
    int idx = blockIdx.x * 256 + threadIdx.x;
    if (idx >= E * 32) return;
    int e = idx >> 5;
    int p = idx & 31;
    int r = rows[e];
    int c = cols[e];
    float v = vals[e];
    float4 f = feat4[c * 32 + p];
    float* hr = h + (long long)r * D + p * 4;
    unsafeAtomicAdd(hr + 0, v * f.x);
    unsafeAtomicAdd(hr + 1, v * f.y);
    unsafeAtomicAdd(hr + 2, v * f.z);
    unsafeAtomicAdd(hr + 3, v * f.w);
}

__global__ __launch_bounds__(256) void fused_gemm_kernel(
    const float* __restrict__ feat, const float* __restrict__ h,
    const float* __restrict__ W1, const float* __restrict__ b1,
    const float* __restrict__ W2, const float* __restrict__ b2,
    float* __restrict__ out, int N)
{
    __shared__ float a_lds[BM][D];
    __shared__ float m_lds[BM][D];
    const int tid = threadIdx.x;
    const int block0 = blockIdx.x * BM;
    const float4* feat4 = (const float4*)feat;
    const float4* h4    = (const float4*)h;
    #pragma unroll
    for (int it = 0; it < 8; ++it) {
        int idx  = tid + it * 256;
        int node = idx >> 5;
        int p    = idx & 31;
        int gnode = block0 + node;
        float4 fv = make_float4(0.f, 0.f, 0.f, 0.f);
        float4 hv = make_float4(0.f, 0.f, 0.f, 0.f);
        if (gnode < N) { fv = feat4[gnode * 32 + p]; hv = h4[gnode * 32 + p]; }
        float4 av = make_float4(fv.x + hv.x, fv.y + hv.y, fv.z + hv.z, fv.w + hv.w);
        float4 mv = make_float4(fv.x * hv.x, fv.y * hv.y, fv.z * hv.z, fv.w * hv.w);
        *(float4*)&a_lds[node][p * 4] = av;
        *(float4*)&m_lds[node][p * 4] = mv;
    }
    __syncthreads();
    const int c = tid & 31;
    const int g = tid >> 5;
    float acc[8][4] = {};
    const float4* W1v = (const float4*)W1;
    const float4* W2v = (const float4*)W2;
    for (int k = 0; k < D; ++k) {
        float4 w1 = W1v[k * 32 + c];
        float4 w2 = W2v[k * 32 + c];
        #pragma unroll
        for (int t = 0; t < 8; ++t) {
            float av = a_lds[g + 8 * t][k];
            float mv = m_lds[g + 8 * t][k];
            acc[t][0] = fmaf(av, w1.x, fmaf(mv, w2.x, acc[t][0]));
            acc[t][1] = fmaf(av, w1.y, fmaf(mv, w2.y, acc[t][1]));
            acc[t][2] = fmaf(av, w1.z, fmaf(mv, w2.z, acc[t][2]));
            acc[t][3] = fmaf(av, w1.w, fmaf(mv, w2.w, acc[t][3]));
        }
    }
    float4 bb1 = ((const float4*)b1)[c];
    float4 bb2 = ((const float4*)b2)[c];
    const float bx = bb1.x + bb2.x, by = bb1.y + bb2.y;
    const float bz = bb1.z + bb2.z, bw = bb1.w + bb2.w;
    #pragma unroll
    for (int t = 0; t < 8; ++t) {
        int gnode = block0 + g + 8 * t;
        if (gnode >= N) continue;
        float4 o;
        o.x = acc[t][0] + bx; o.y = acc[t][1] + by;
        o.z = acc[t][2] + bz; o.w = acc[t][3] + bw;
        o.x = (o.x >= 0.f) ? o.x : 0.01f * o.x;
        o.y = (o.y >= 0.f) ? o.y : 0.01f * o.y;
        o.z = (o.z >= 0.f) ? o.z : 0.01f * o.z;
        o.w = (o.w >= 0.f) ? o.w : 0.01f * o.w;
        ((float4*)out)[gnode * 32 + c] = o;
    }
}

extern "C" void kernel_launch(void* const* d_in, const int* in_sizes, int n_in,
                              void* d_out, int out_size, void* d_ws, size_t ws_size,
                              hipStream_t stream) {
    const float* feat = (const float*)d_in[0];
    const int*   rows = (const int*)d_in[1];
    const int*   cols = (const int*)d_in[2];
    const float* vals = (const float*)d_in[3];
    const float* W1   = (const float*)d_in[4];
    const float* b1   = (const float*)d_in[5];
    const float* W2   = (const float*)d_in[6];
    const float* b2   = (const float*)d_in[7];

    const int N = in_sizes[0] / D;
    const int E = in_sizes[1];
    float* out = (float*)d_out;

    const int NBK  = (N + 63) >> 6;           // 64-row buckets (1563)
    const int Npad = NBK << 6;

    // --- Tier-1: ambf | featbf | WT | bsedge(padded) | gcur
    size_t off = 0;
    unsigned char* ambf = (unsigned char*)d_ws;                    off += (size_t)Npad * 512;
    unsigned short* featbf = (unsigned short*)((char*)d_ws + off); off += (size_t)N * D * 2;
    off = (off + 15) & ~(size_t)15;
    unsigned short* WT = (unsigned short*)((char*)d_ws + off);     off += 128 * 256 * 2;
    off = (off + 15) & ~(size_t)15;
    uint2* bsedge = (uint2*)((char*)d_ws + off);                   off += (size_t)NBK * SLOT * 8;
    int* gcur = (int*)((char*)d_ws + off);                         off += (size_t)NBK * 4;
    size_t need1 = off;

    if (ws_size >= need1 && NBK <= 2048 && N <= (1 << 17)) {
        hipMemsetAsync(gcur, 0, (size_t)NBK * sizeof(int), stream);
        prep_kernel<<<1024, 256, 0, stream>>>(
            (const float4*)feat, (ushort4*)featbf, N * 32, W1, W2, WT);
        bucket_scatter_kernel<<<(E + 4095) / 4096, 256, 0, stream>>>(
            rows, cols, vals, gcur, bsedge, E, NBK);
        spmm_sort64_kernel<<<NBK, 512, 0, stream>>>(
            (const ushort8_t*)featbf, gcur, bsedge, ambf, N);
        mfma_gemm2_kernel<<<(N + BM - 1) / BM, 256, 0, stream>>>(
            ambf, WT, b1, b2, out, N);
        return;
    }

    // --- Tier-2: round-3 fp32 CSR path ---
    const int NB = (N + 1023) / 1024;
    off = 0;
    float* h = (float*)d_ws;                           off += (size_t)N * D * 4;
    int* row_start2 = (int*)((char*)d_ws + off);       off += (size_t)(N + 1) * 4;
    int* cursor2    = (int*)((char*)d_ws + off);       off += (size_t)N * 4;
    off = (off + 15) & ~(size_t)15;
    uint2* sedge2   = (uint2*)((char*)d_ws + off);     off += (size_t)E * 8;
    off = (off + 15) & ~(size_t)15;
    unsigned short* WT2 = (unsigned short*)((char*)d_ws + off); off += 128 * 256 * 2;
    int* btot2 = (int*)((char*)d_ws + off);            off += (size_t)NB * 4;
    int* boff2 = (int*)((char*)d_ws + off);            off += (size_t)NB * 4;
    size_t need2 = off;

    if (ws_size >= need2 && NB <= 1024) {
        hipMemsetAsync(row_start2, 0, (size_t)(N + 1) * sizeof(int), stream);
        wconv_kernel<<<128, 256, 0, stream>>>(W1, W2, WT2);
        hist_kernel<<<(E + 255) / 256, 256, 0, stream>>>(rows, row_start2, E);
        scan_pass1<<<NB, 256, 0, stream>>>(row_start2, btot2, N);
        scan_pass2<<<1, 1024, 0, stream>>>(btot2, boff2, NB);
        scan_pass3<<<NB, 256, 0, stream>>>(row_start2, cursor2, boff2, N, E);
        scatter_sort_kernel<<<(E + 255) / 256, 256, 0, stream>>>(
            rows, cols, vals, cursor2, sedge2, E);
        spmm_kernel<<<(N * 64 + 255) / 256, 256, 0, stream>>>(
            (const float2*)feat, row_start2, sedge2, (float2*)h, N);
        mfma_gemm_kernel<<<(N + BM - 1) / BM, 256, 0, stream>>>(
            (const float4*)feat, (const float4*)h, WT2, b1, b2, out, N);
        return;
    }

    // --- Tier-3: atomic scatter + VALU GEMM ---
    size_t hbytes = (size_t)N * D * sizeof(float);
    float* hh = (ws_size >= hbytes) ? (float*)d_ws : out;
    hipMemsetAsync(hh, 0, hbytes, stream);
    edge_scatter_kernel<<<((size_t)E * 32 + 255) / 256, 256, 0, stream>>>(
        (const float4*)feat, rows, cols, vals, hh, E);
    fused_gemm_kernel<<<(N + BM - 1) / BM, 256, 0, stream>>>(
        feat, hh, W1, b1, W2, b2, out, N);
}